// Round 16
// baseline (243.360 us; speedup 1.0000x reference)
//
#include <hip/hip_runtime.h>

// TrilinearInterpolation: 33^3 x 3ch LUT applied to 8x3x1024x1024 image.
// d_out = [lut copy (107811)] ++ [output (25165824)].
//
// R14 post-mortem: D (3 barriers, lock-step phases) = 91.3us with NOTHING
// saturated (VALU 40%, LDS 32%, TA 30%, HBM 30%) -> phase-bubble-bound.
// This round: barrier-free wave-local exchange. Each wave gathers/exchanges
// only its own 64 rows in its own 8KB LDS slice; owner cells via __shfl.
// Zero __syncthreads -> waves pipeline independently across the CU.

typedef float f32x4 __attribute__((ext_vector_type(4)));

#define DIM    33
#define D2     (DIM * DIM)
#define SHIFT  (DIM * DIM * DIM)
#define LUT_ELEMS (3 * SHIFT)
#define NCELL  32768
#define PLANE  1048576
#define NPIX   (8 * PLANE)

// ---------- build 128B-padded records: cell -> 8 corners x 3ch (+8 pad) ----------
__global__ __launch_bounds__(256) void build_cells128_kernel(
    const float* __restrict__ lut, float* __restrict__ cells) {
    int t = blockIdx.x * 256 + threadIdx.x;     // NCELL*32 threads
    int cell = t >> 5;
    int j = t & 31;
    float v = 0.0f;
    if (j < 24) {
        int corner = j / 3;
        int ch = j - corner * 3;
        int ri = cell & 31, gi = (cell >> 5) & 31, bi = cell >> 10;
        int dr = corner & 1, dg = (corner >> 1) & 1, db = corner >> 2;
        v = lut[ch * SHIFT + (bi + db) * D2 + (gi + dg) * DIM + (ri + dr)];
    }
    cells[t] = v;
}

// ---------- shared helpers ----------
__device__ __forceinline__ void decode_px(float r, float g, float bl,
                                          int& cell, float& rd, float& gd, float& bd) {
    const float BIN = (float)(1.000001 / 32.0);
    float rs = r / BIN, gs = g / BIN, bs = bl / BIN;
    float rf = floorf(rs), gf = floorf(gs), bf = floorf(bs);
    rd = rs - rf; gd = gs - gf; bd = bs - bf;
    cell = (((int)bf) << 10) | (((int)gf) << 5) | ((int)rf);
}

__device__ __forceinline__ void tri_out(const float* v, float rd, float gd, float bd,
                                        float& o0, float& o1, float& o2) {
    float omr = 1.0f - rd, omg = 1.0f - gd, omb = 1.0f - bd;
    float w000 = omr*omg*omb, w100 = rd*omg*omb, w010 = omr*gd*omb, w110 = rd*gd*omb;
    float w001 = omr*omg*bd,  w101 = rd*omg*bd,  w011 = omr*gd*bd,  w111 = rd*gd*bd;
    o0 = w000*v[0] + w100*v[3] + w010*v[6]  + w110*v[9]  + w001*v[12] + w101*v[15] + w011*v[18] + w111*v[21];
    o1 = w000*v[1] + w100*v[4] + w010*v[7]  + w110*v[10] + w001*v[13] + w101*v[16] + w011*v[19] + w111*v[22];
    o2 = w000*v[2] + w100*v[5] + w010*v[8]  + w110*v[11] + w001*v[14] + w101*v[17] + w011*v[20] + w111*v[23];
}

// ---------- barrier-free wave-local coop exchange ----------
__global__ __launch_bounds__(256) void apply_wave_kernel(
    const float* __restrict__ x, const float* __restrict__ cells,
    float* __restrict__ out) {
    __shared__ float recs[256 * 32];   // 32 KB; wave w owns rows [w*64, w*64+64)

    const int tid = threadIdx.x;
    const int t = blockIdx.x * 256 + tid;
    const int b = t >> 20;
    const int p = t & (PLANE - 1);
    const float* xb = x + (size_t)b * (3 * PLANE) + p;
    float r  = __builtin_nontemporal_load(xb);
    float g  = __builtin_nontemporal_load(xb + PLANE);
    float bl = __builtin_nontemporal_load(xb + 2 * PLANE);
    int cell; float rd, gd, bd;
    decode_px(r, g, bl, cell, rd, gd, bd);

    const int lane  = tid & 63;
    const int wrow0 = tid & 192;          // wave * 64 = first row of this wave
    const int grp   = lane >> 2;          // 4-lane group id, 0..15
    // 8-lane-phase bank balance: chunk ids cover 0..7 once per phase after XOR.
    const int cl0 = (lane & 3) | ((grp & 1) << 2);
    const int cl1 = cl0 ^ 4;
    const int kk  = grp & 7;              // == row_id & 7 (row_id = 16i+grp)

    // Phase 1: issue all 8 gather loads (addresses via __shfl of owner cells).
    f32x4 va[4], vb[4];
    int srcl[4];
    #pragma unroll
    for (int i = 0; i < 4; ++i) {
        int src_lane = i * 16 + grp;                   // owner lane of row
        int c = __shfl(cell, src_lane, 64);
        const f32x4* src = (const f32x4*)(cells + (size_t)c * 32);
        va[i] = src[cl0];
        vb[i] = src[cl1];
        srcl[i] = src_lane;
    }
    // Phase 2: write into this wave's private LDS slice (no barrier needed;
    // wave-local RAW ordering via compiler-inserted waitcnts).
    #pragma unroll
    for (int i = 0; i < 4; ++i) {
        f32x4* row = (f32x4*)(recs + (wrow0 + srcl[i]) * 32);
        row[cl0 ^ kk] = va[i];
        row[cl1 ^ kk] = vb[i];
    }

    // Phase 3: read own row (swizzled) and finish.
    int k = lane & 7;
    const f32x4* row = (const f32x4*)(recs + tid * 32);   // own row == tid
    float v[24];
    #pragma unroll
    for (int c = 0; c < 6; ++c)
        *(f32x4*)(v + 4 * c) = row[c ^ k];

    float o0, o1, o2;
    tri_out(v, rd, gd, bd, o0, o1, o2);
    float* ob = out + (size_t)b * (3 * PLANE) + p;
    __builtin_nontemporal_store(o0, ob);
    __builtin_nontemporal_store(o1, ob + PLANE);
    __builtin_nontemporal_store(o2, ob + 2 * PLANE);
}

// ---------- fallback: direct gather from original layout ----------
__global__ __launch_bounds__(256) void apply_direct_kernel(
    const float* __restrict__ x, const float* __restrict__ lut,
    float* __restrict__ out) {
    int t = blockIdx.x * 256 + threadIdx.x;
    int b = t >> 20;
    int p = t & (PLANE - 1);
    const float* xb = x + (size_t)b * (3 * PLANE) + p;
    int cell; float rd, gd, bd;
    decode_px(xb[0], xb[PLANE], xb[2 * PLANE], cell, rd, gd, bd);
    int ri = cell & 31, gi = (cell >> 5) & 31, bi = cell >> 10;
    int id000 = ri + gi * DIM + bi * D2;

    float omr = 1.0f - rd, omg = 1.0f - gd, omb = 1.0f - bd;
    float w000 = omr*omg*omb, w100 = rd*omg*omb, w010 = omr*gd*omb, w110 = rd*gd*omb;
    float w001 = omr*omg*bd,  w101 = rd*omg*bd,  w011 = omr*gd*bd,  w111 = rd*gd*bd;

    float* ob = out + (size_t)b * (3 * PLANE) + p;
    #pragma unroll
    for (int ch = 0; ch < 3; ++ch) {
        const float* L = lut + ch * SHIFT + id000;
        float acc = w000 * L[0]        + w100 * L[1]
                  + w010 * L[DIM]      + w110 * L[DIM + 1]
                  + w001 * L[D2]       + w101 * L[D2 + 1]
                  + w011 * L[D2 + DIM] + w111 * L[D2 + DIM + 1];
        ob[(size_t)ch * PLANE] = acc;
    }
}

extern "C" void kernel_launch(void* const* d_in, const int* in_sizes, int n_in,
                              void* d_out, int out_size, void* d_ws, size_t ws_size,
                              hipStream_t stream) {
    const float* lut = (const float*)d_in[1];
    const float* x   = (const float*)d_in[2];
    float* out = (float*)d_out;

    (void)hipMemcpyAsync(out, lut, (size_t)LUT_ELEMS * sizeof(float),
                         hipMemcpyDeviceToDevice, stream);

    float* outimg = out + LUT_ELEMS;
    const size_t bytes128 = (size_t)NCELL * 32 * sizeof(float);  // 4 MiB

    if (ws_size >= bytes128) {
        float* cells = (float*)d_ws;
        build_cells128_kernel<<<NCELL * 32 / 256, 256, 0, stream>>>(lut, cells);
        apply_wave_kernel<<<NPIX / 256, 256, 0, stream>>>(x, cells, outimg);
    } else {
        apply_direct_kernel<<<NPIX / 256, 256, 0, stream>>>(x, lut, outimg);
    }
}